// Round 3
// baseline (319.698 us; speedup 1.0000x reference)
//
#include <hip/hip_runtime.h>

#define EPSF 1e-5f
#define NSEG 2048
#define BM   128   // x-rows per tile
#define NTHR 512   // 8 waves

typedef short s16x8 __attribute__((ext_vector_type(8)));
typedef float f32x16 __attribute__((ext_vector_type(16)));

__device__ __forceinline__ unsigned short f2bf(float f) {
  unsigned int u = __float_as_uint(f);
  u += 0x7FFFu + ((u >> 16) & 1u);  // RNE; data has no NaN/Inf
  return (unsigned short)(u >> 16);
}
__device__ __forceinline__ float bf2f(unsigned short h) {
  return __uint_as_float(((unsigned int)h) << 16);
}

struct LayerP { const float *W, *b, *g, *be, *m, *v; };

// Fold BN into weights: W'[c,k] = W[c,k]*s_c (bf16), bias'_c = b_c*s_c + be_c - m_c*s_c
__global__ void prep_kernel(LayerP p0, LayerP p1, LayerP p2,
                            unsigned short* __restrict__ wsW,
                            float* __restrict__ biasf) {
  const int L = blockIdx.x;
  LayerP p = (L == 0) ? p0 : ((L == 1) ? p1 : p2);
  const int t = threadIdx.x;
  uint2* wdst = (uint2*)(wsW + L * 16384);
  const float4* wsrc = (const float4*)p.W;
  for (int i = 0; i < 16; ++i) {
    int idx4 = t + i * 256;            // 4096 float4 = 128x128
    int c = idx4 >> 5;                 // 32 float4 per row
    float s = p.g[c] * rsqrtf(p.v[c] + EPSF);
    float4 w = wsrc[idx4];
    unsigned lo = (unsigned)f2bf(w.x * s) | ((unsigned)f2bf(w.y * s) << 16);
    unsigned hi = (unsigned)f2bf(w.z * s) | ((unsigned)f2bf(w.w * s) << 16);
    wdst[idx4] = make_uint2(lo, hi);
  }
  if (t < 128) {
    float s = p.g[t] * rsqrtf(p.v[t] + EPSF);
    biasf[L * 128 + t] = p.b[t] * s + p.be[t] - p.m[t] * s;
  }
}

// LDS layout: in_tile row = 256B = 16 chunks of 16B; chunk stored at (chunk ^ (row&15)).
// Conflict-free for b128 frag reads, 8B epilogue/stage writes, and 4B segment reads.
__device__ __forceinline__ int lds_byte(int row, int elem) {
  return row * 256 + (((elem >> 3) ^ (row & 15)) << 4) + (elem & 7) * 2;
}

// Persistent fused encoder: weights in registers, x-tile in LDS, 3 layers, segment atomics.
__global__ __launch_bounds__(NTHR, 2)
void enc_kernel(const float* __restrict__ x, const int* __restrict__ batch,
                const unsigned short* __restrict__ wsW,
                const float* __restrict__ biasf,
                float* __restrict__ seg_sum, unsigned* __restrict__ seg_max,
                unsigned* __restrict__ seg_cnt, int N, int ntiles) {
  __shared__ __attribute__((aligned(16))) unsigned char in_tile[BM * 256];
  __shared__ __attribute__((aligned(16))) float bias_lds[384];
  __shared__ int sb[BM];

  const int t = threadIdx.x;
  const int lane = t & 63;
  const int l31 = lane & 31, hi = lane >> 5;
  const int wv = t >> 6;
  const int wc = wv & 3, wr = wv >> 2;      // 4 ch-groups x 2 row-groups
  const int r0 = wr * 64 + l31;             // first x-row this lane produces/consumes

  // ---- one-time: all 3 layers' A-fragments into registers (96 VGPR) ----
  s16x8 wreg[3][8];
  {
    const unsigned short* wp = wsW + (wc * 32 + l31) * 128 + hi * 8;
#pragma unroll
    for (int L = 0; L < 3; ++L)
#pragma unroll
      for (int j = 0; j < 8; ++j)
        wreg[L][j] = *(const s16x8*)(wp + L * 16384 + j * 16);
  }
  if (t < 384) bias_lds[t] = biasf[t];

  // ---- prefetch first tile into registers ----
  const int row8 = t >> 5, col8 = t & 31;   // this thread's (row, float4-col) in the tile
  int tile = blockIdx.x;
  float4 xr[8];
  int sreg = -1;
  {
    const float4* xs = (const float4*)x;
    int R0 = tile * BM;
#pragma unroll
    for (int i = 0; i < 8; ++i) {
      int row = row8 + i * 16;
      int r = R0 + row;
      xr[i] = (r < N) ? xs[(size_t)r * 32 + col8] : make_float4(0.f, 0.f, 0.f, 0.f);
    }
    if (t < BM) sreg = (R0 + t < N) ? batch[R0 + t] : -1;
  }

  while (tile < ntiles) {
    // ---- convert prefetched x -> LDS (bf16, swizzled), publish sb ----
    if (t < BM) sb[t] = sreg;
#pragma unroll
    for (int i = 0; i < 8; ++i) {
      int row = row8 + i * 16;
      float4 v = xr[i];
      unsigned lo = (unsigned)f2bf(v.x) | ((unsigned)f2bf(v.y) << 16);
      unsigned h2 = (unsigned)f2bf(v.z) | ((unsigned)f2bf(v.w) << 16);
      *(uint2*)&in_tile[lds_byte(row, col8 * 4)] = make_uint2(lo, h2);
    }
    // ---- issue prefetch for next tile (completes under 3 layers of compute) ----
    int ntile = tile + gridDim.x;
    {
      const float4* xs = (const float4*)x;
      int R0n = ntile * BM;
#pragma unroll
      for (int i = 0; i < 8; ++i) {
        int row = row8 + i * 16;
        int r = R0n + row;
        xr[i] = (ntile < ntiles && r < N) ? xs[(size_t)r * 32 + col8]
                                          : make_float4(0.f, 0.f, 0.f, 0.f);
      }
      sreg = (t < BM && ntile < ntiles && R0n + t < N) ? batch[R0n + t] : -1;
    }
    __syncthreads();

    // ---- 3 fused layers ----
#pragma unroll
    for (int L = 0; L < 3; ++L) {
      f32x16 acc0 = {0,0,0,0,0,0,0,0,0,0,0,0,0,0,0,0};
      f32x16 acc1 = {0,0,0,0,0,0,0,0,0,0,0,0,0,0,0,0};
      const int swz0 = (r0 & 15);
#pragma unroll
      for (int j = 0; j < 8; ++j) {
        int c = 2 * j + hi;             // 16B chunk index (k = j*16 + hi*8)
        s16x8 b0 = *(const s16x8*)&in_tile[r0 * 256 + ((c ^ swz0) << 4)];
        s16x8 b1 = *(const s16x8*)&in_tile[(r0 + 32) * 256 + ((c ^ swz0) << 4)];
        acc0 = __builtin_amdgcn_mfma_f32_32x32x16_bf16(wreg[L][j], b0, acc0, 0, 0, 0);
        acc1 = __builtin_amdgcn_mfma_f32_32x32x16_bf16(wreg[L][j], b1, acc1, 0, 0, 0);
      }
      __syncthreads();  // all in_tile reads done before overwrite

      // bias + ReLU, pack bf16, write back (swizzled)
      // C/D: col(xrow)=lane&31, row(ch)=(reg&3)+8*(reg>>2)+4*hi
#pragma unroll
      for (int mt = 0; mt < 2; ++mt) {
        const f32x16 A = mt ? acc1 : acc0;
        const int r = r0 + mt * 32;
#pragma unroll
        for (int g = 0; g < 4; ++g) {
          int ch = wc * 32 + 4 * hi + 8 * g;
          const float4 bb = *(const float4*)&bias_lds[L * 128 + ch];
          float v0 = fmaxf(A[4 * g + 0] + bb.x, 0.f);
          float v1 = fmaxf(A[4 * g + 1] + bb.y, 0.f);
          float v2 = fmaxf(A[4 * g + 2] + bb.z, 0.f);
          float v3 = fmaxf(A[4 * g + 3] + bb.w, 0.f);
          unsigned lo = (unsigned)f2bf(v0) | ((unsigned)f2bf(v1) << 16);
          unsigned h2 = (unsigned)f2bf(v2) | ((unsigned)f2bf(v3) << 16);
          // chunk = wc*4+g (4*hi stays inside chunk); byte-in-chunk = hi*8
          *(uint2*)&in_tile[r * 256 + ((((wc << 2) + g) ^ (r & 15)) << 4) + hi * 8] =
              make_uint2(lo, h2);
        }
      }
      __syncthreads();
    }

    // ---- per-segment counts (one atomic per run; batch sorted) ----
    if (t < BM) {
      int seg = sb[t];
      if (seg >= 0 && (t == 0 || sb[t - 1] != seg)) {
        int e = t + 1;
        while (e < BM && sb[e] == seg) ++e;
        atomicAdd(&seg_cnt[seg], (unsigned)(e - t));
      }
    }

    // ---- segment sum/max: wave q owns rows [16q,16q+16), lane owns col-pair ----
    {
      int cp = (t & 63) * 2;
      int q = t >> 6;
      float s0 = 0.f, s1 = 0.f, m0 = 0.f, m1 = 0.f;
      int cur = sb[q * 16];
      for (int r = q * 16; r < q * 16 + 16; ++r) {
        int seg = sb[r];
        if (seg != cur) {
          if (cur >= 0) {
            if (s0 != 0.f || m0 != 0.f) { atomicAdd(&seg_sum[cur * 128 + cp], s0); atomicMax((int*)&seg_max[cur * 128 + cp], __float_as_int(m0)); }
            if (s1 != 0.f || m1 != 0.f) { atomicAdd(&seg_sum[cur * 128 + cp + 1], s1); atomicMax((int*)&seg_max[cur * 128 + cp + 1], __float_as_int(m1)); }
          }
          s0 = s1 = m0 = m1 = 0.f;
          cur = seg;
        }
        if (seg >= 0) {
          unsigned pv = *(const unsigned*)&in_tile[lds_byte(r, cp)];
          float v0 = bf2f((unsigned short)(pv & 0xffffu));
          float v1 = bf2f((unsigned short)(pv >> 16));
          s0 += v0; s1 += v1;
          m0 = fmaxf(m0, v0); m1 = fmaxf(m1, v1);
        }
      }
      if (cur >= 0) {
        if (s0 != 0.f || m0 != 0.f) { atomicAdd(&seg_sum[cur * 128 + cp], s0); atomicMax((int*)&seg_max[cur * 128 + cp], __float_as_int(m0)); }
        if (s1 != 0.f || m1 != 0.f) { atomicAdd(&seg_sum[cur * 128 + cp + 1], s1); atomicMax((int*)&seg_max[cur * 128 + cp + 1], __float_as_int(m1)); }
      }
    }
    __syncthreads();  // in_tile reused next iteration
    tile = ntile;
  }
}

// out[s,o] = BN( [sum|max|mean] @ Wo^T + bo )
__global__ __launch_bounds__(128)
void proj_kernel(const float* __restrict__ seg_sum, const unsigned* __restrict__ seg_max,
                 const unsigned* __restrict__ seg_cnt,
                 const float* __restrict__ Wo, const float* __restrict__ bo,
                 const float* __restrict__ go, const float* __restrict__ beo,
                 const float* __restrict__ mo, const float* __restrict__ vo,
                 float* __restrict__ out) {
  __shared__ __attribute__((aligned(16))) float agg[384];
  __shared__ float part[64];
  const int s = blockIdx.x, t = threadIdx.x;
  float cinv = 1.f / fmaxf((float)seg_cnt[s], 1.f);
  for (int i = t; i < 384; i += 128) {
    float v;
    if (i < 128)      v = seg_sum[s * 128 + i];
    else if (i < 256) v = __uint_as_float(seg_max[s * 128 + i - 128]);
    else              v = seg_sum[s * 128 + i - 256] * cinv;
    agg[i] = v;
  }
  __syncthreads();
  const int o = t & 63, hf = t >> 6;
  const float4* wrow = (const float4*)(Wo + o * 384 + hf * 192);
  float acc = 0.f;
#pragma unroll 8
  for (int k4 = 0; k4 < 48; ++k4) {
    float4 w = wrow[k4];
    float4 a = *(const float4*)&agg[hf * 192 + k4 * 4];
    acc += w.x * a.x + w.y * a.y + w.z * a.z + w.w * a.w;
  }
  if (hf) part[o] = acc;
  __syncthreads();
  if (!hf) {
    acc += part[o];
    float sc = go[o] * rsqrtf(vo[o] + EPSF);
    out[s * 64 + o] = (acc + bo[o] - mo[o]) * sc + beo[o];
  }
}

extern "C" void kernel_launch(void* const* d_in, const int* in_sizes, int n_in,
                              void* d_out, int out_size, void* d_ws, size_t ws_size,
                              hipStream_t stream) {
  (void)n_in; (void)out_size; (void)ws_size;
  const float* x = (const float*)d_in[0];
  const int* batch = (const int*)d_in[1];
  LayerP P0{(const float*)d_in[2],  (const float*)d_in[3],  (const float*)d_in[4],
            (const float*)d_in[5],  (const float*)d_in[6],  (const float*)d_in[7]};
  LayerP P1{(const float*)d_in[8],  (const float*)d_in[9],  (const float*)d_in[10],
            (const float*)d_in[11], (const float*)d_in[12], (const float*)d_in[13]};
  LayerP P2{(const float*)d_in[14], (const float*)d_in[15], (const float*)d_in[16],
            (const float*)d_in[17], (const float*)d_in[18], (const float*)d_in[19]};
  const float* Wo  = (const float*)d_in[20];
  const float* bo  = (const float*)d_in[21];
  const float* go  = (const float*)d_in[22];
  const float* beo = (const float*)d_in[23];
  const float* mo  = (const float*)d_in[24];
  const float* vo  = (const float*)d_in[25];
  const int N = in_sizes[0] / 128;

  char* ws = (char*)d_ws;
  float*    seg_sum = (float*)ws;                          // 2048*128 f32 = 1 MiB
  unsigned* seg_max = (unsigned*)(ws + (1u << 20));        // 1 MiB (float bits, >=0)
  unsigned* seg_cnt = (unsigned*)(ws + (2u << 20));        // 8 KiB
  unsigned short* wsW = (unsigned short*)(ws + (2u << 20) + 8192);      // 3*128*128 bf16
  float* biasf = (float*)(ws + (2u << 20) + 8192 + 98304);              // 3*128 f32

  hipMemsetAsync(d_ws, 0, (size_t)(2u << 20) + 8192, stream);
  prep_kernel<<<3, 256, 0, stream>>>(P0, P1, P2, wsW, biasf);
  const int ntiles = (N + BM - 1) / BM;
  enc_kernel<<<256, NTHR, 0, stream>>>(x, batch, wsW, biasf, seg_sum, seg_max, seg_cnt,
                                       N, ntiles);
  proj_kernel<<<NSEG, 128, 0, stream>>>(seg_sum, seg_max, seg_cnt, Wo, bo, go, beo, mo, vo,
                                        (float*)d_out);
}

// Round 5
// 143.957 us; speedup vs baseline: 2.2208x; 2.2208x over previous
//
#include <hip/hip_runtime.h>

#define EPSF 1e-5f
#define NSEG 2048
#define NTHR 512
#define NBLK 256
#define STRIDE 2048  // NBLK * 8 waves

typedef short s16x8 __attribute__((ext_vector_type(8)));
typedef float f32x16 __attribute__((ext_vector_type(16)));
typedef unsigned u32;

__device__ __forceinline__ u32 f2bfu(float f) {
  u32 u = __float_as_uint(f);
  u += 0x7FFFu + ((u >> 16) & 1u);  // RNE; no NaN/Inf in data
  return u >> 16;
}
__device__ __forceinline__ u32 pk2(float a, float b) {
  return f2bfu(a) | (f2bfu(b) << 16);
}
__device__ __forceinline__ float bf2f(u32 h) {
  return __uint_as_float(h << 16);
}

union FragU { s16x8 v; u32 u[4]; };

struct LayerP { const float *W, *b, *g, *be, *m, *v; };

// Fold BN into weights: W'[c,k] = W[c,k]*s_c (bf16), bias'_c = b_c*s_c + be_c - m_c*s_c
__global__ void prep_kernel(LayerP p0, LayerP p1, LayerP p2,
                            unsigned short* __restrict__ wsW,
                            float* __restrict__ biasf) {
  const int L = blockIdx.x;
  LayerP p = (L == 0) ? p0 : ((L == 1) ? p1 : p2);
  const int t = threadIdx.x;
  uint2* wdst = (uint2*)(wsW + L * 16384);
  const float4* wsrc = (const float4*)p.W;
  for (int i = 0; i < 16; ++i) {
    int idx4 = t + i * 256;            // 4096 float4 = 128x128
    int c = idx4 >> 5;
    float s = p.g[c] * rsqrtf(p.v[c] + EPSF);
    float4 w = wsrc[idx4];
    wdst[idx4] = make_uint2(pk2(w.x * s, w.y * s), pk2(w.z * s, w.w * s));
  }
  if (t < 128) {
    float s = p.g[t] * rsqrtf(p.v[t] + EPSF);
    biasf[L * 128 + t] = p.b[t] * s + p.be[t] - p.m[t] * s;
  }
}

// Barrier-free persistent encoder: each wave owns independent 32-row tiles.
// LDS: [0,98304) swizzled weights (3 layers); [98304,131072) 8x4KB wave-private h3.
__global__ __launch_bounds__(NTHR, 2)
void enc_kernel(const float* __restrict__ x, const int* __restrict__ batch,
                const unsigned short* __restrict__ wsW, const float* __restrict__ biasf,
                float* __restrict__ seg_sum, int* __restrict__ seg_max,
                u32* __restrict__ seg_cnt, int N, int ntiles) {
  __shared__ __attribute__((aligned(16))) unsigned char lds[131072];
  __shared__ __attribute__((aligned(16))) float bias_lds[384];
  const int t = threadIdx.x;
  const int lane = t & 63, wv = t >> 6;
  const int l31 = lane & 31, hi = lane >> 5;
  const int swz = l31 & 15;
  const int xaddr = (lane ^ 32) << 2;  // ds_bpermute byte-addr of partner lane

  // one-time: stage weights global->LDS with chunk^row swizzle
  {
    const uint4* src = (const uint4*)wsW;
#pragma unroll
    for (int i = 0; i < 12; ++i) {
      int idx = t + i * NTHR;          // 6144 x 16B
      int byte = idx << 4;
      int dst = byte ^ (((byte >> 8) & 15) << 4);  // chunk ^= row&15
      *(uint4*)&lds[dst] = src[idx];
    }
  }
  if (t < 384) bias_lds[t] = biasf[t];
  __syncthreads();                      // the only block barrier

  const int hbase = 98304 + wv * 4096;
  const float4* x4 = (const float4*)x;
  const int g0 = blockIdx.x * 8 + wv;

  float4 xr[16];
  int sreg;
  {  // prologue prefetch (tile g0 always < ntiles: ntiles=15625 >= STRIDE)
    int r = g0 * 32 + l31;
    bool ok = r < N;
#pragma unroll
    for (int s = 0; s < 8; ++s) {
      size_t base = (size_t)r * 32 + s * 4 + hi * 2;
      xr[2 * s]     = ok ? x4[base]     : make_float4(0.f, 0.f, 0.f, 0.f);
      xr[2 * s + 1] = ok ? x4[base + 1] : make_float4(0.f, 0.f, 0.f, 0.f);
    }
    sreg = ok ? batch[r] : -1;
  }

  for (int tile = g0; tile < ntiles; tile += STRIDE) {
    // convert prefetched x -> B-fragments (lane = row l31, k = 16s+8hi+j)
    FragU frag[8];
#pragma unroll
    for (int s = 0; s < 8; ++s) {
      float4 a = xr[2 * s], b = xr[2 * s + 1];
      frag[s].u[0] = pk2(a.x, a.y);
      frag[s].u[1] = pk2(a.z, a.w);
      frag[s].u[2] = pk2(b.x, b.y);
      frag[s].u[3] = pk2(b.z, b.w);
    }
    const int scur = sreg;
    {  // issue prefetch for next tile (lands under 3 layers of compute)
      int nt = tile + STRIDE;
      int r = nt * 32 + l31;
      bool ok = (nt < ntiles) && (r < N);
#pragma unroll
      for (int s = 0; s < 8; ++s) {
        size_t base = (size_t)r * 32 + s * 4 + hi * 2;
        xr[2 * s]     = ok ? x4[base]     : make_float4(0.f, 0.f, 0.f, 0.f);
        xr[2 * s + 1] = ok ? x4[base + 1] : make_float4(0.f, 0.f, 0.f, 0.f);
      }
      sreg = ok ? batch[r] : -1;
    }

    f32x16 accs[4];
#pragma unroll
    for (int L = 0; L < 3; ++L) {
      const int wb = L * 32768 + l31 * 256;
#pragma unroll
      for (int cg = 0; cg < 4; ++cg) {
        f32x16 z = {0,0,0,0,0,0,0,0,0,0,0,0,0,0,0,0};
        accs[cg] = z;
      }
#pragma unroll
      for (int s = 0; s < 8; ++s) {
#pragma unroll
        for (int cg = 0; cg < 4; ++cg) {
          const s16x8 a =
              *(const s16x8*)&lds[wb + cg * 8192 + (((2 * s + hi) ^ swz) << 4)];
          accs[cg] = __builtin_amdgcn_mfma_f32_32x32x16_bf16(a, frag[s].v, accs[cg], 0, 0, 0);
        }
      }
      if (L < 2) {
        // bias + relu (validated float4 pattern), pack, half-exchange via ds_bpermute
#pragma unroll
        for (int cg = 0; cg < 4; ++cg) {
          float tr[16];
#pragma unroll
          for (int q = 0; q < 4; ++q) {
            int ch = cg * 32 + 4 * hi + 8 * q;   // C/D: c = (r&3) + 8*(r>>2) + 4*hi
            const float4 bb = *(const float4*)&bias_lds[L * 128 + ch];
            tr[4 * q + 0] = fmaxf(accs[cg][4 * q + 0] + bb.x, 0.f);
            tr[4 * q + 1] = fmaxf(accs[cg][4 * q + 1] + bb.y, 0.f);
            tr[4 * q + 2] = fmaxf(accs[cg][4 * q + 2] + bb.z, 0.f);
            tr[4 * q + 3] = fmaxf(accs[cg][4 * q + 3] + bb.w, 0.f);
          }
#pragma unroll
          for (int kh = 0; kh < 2; ++kh) {
            u32 pw0 = pk2(tr[8 * kh + 0], tr[8 * kh + 1]);  // c = 16kh+{0,1}+4hi'
            u32 pw1 = pk2(tr[8 * kh + 2], tr[8 * kh + 3]);  // c = 16kh+{2,3}+4hi'
            u32 pu0 = pk2(tr[8 * kh + 4], tr[8 * kh + 5]);  // c = 16kh+8+{0,1}+4hi'
            u32 pu1 = pk2(tr[8 * kh + 6], tr[8 * kh + 7]);  // c = 16kh+8+{2,3}+4hi'
            u32 cw0 = (u32)__builtin_amdgcn_ds_bpermute(xaddr, (int)pw0);
            u32 cw1 = (u32)__builtin_amdgcn_ds_bpermute(xaddr, (int)pw1);
            u32 cu0 = (u32)__builtin_amdgcn_ds_bpermute(xaddr, (int)pu0);
            u32 cu1 = (u32)__builtin_amdgcn_ds_bpermute(xaddr, (int)pu1);
            // target frag[2cg+kh]: u[0,1] = c 16kh+8hi+{0..3}, u[2,3] = +{4..7}
            frag[2 * cg + kh].u[0] = hi ? cu0 : pw0;
            frag[2 * cg + kh].u[1] = hi ? cu1 : pw1;
            frag[2 * cg + kh].u[2] = hi ? pu0 : cw0;
            frag[2 * cg + kh].u[3] = hi ? pu1 : cw1;
          }
        }
      }
    }

    // ---- segment phase: wave-private LDS, two 16-row halves, no barriers ----
    float s0 = 0.f, s1 = 0.f, m0 = 0.f, m1 = 0.f;
    int cur = -1, cnt = 0;
#pragma unroll
    for (int half = 0; half < 2; ++half) {
      if ((l31 >> 4) == half) {  // write my row (l31) with bias+relu applied
#pragma unroll
        for (int cg = 0; cg < 4; ++cg)
#pragma unroll
          for (int q = 0; q < 4; ++q) {
            int ch = cg * 32 + 4 * hi + 8 * q;
            const float4 bb = *(const float4*)&bias_lds[256 + ch];
            float e0 = fmaxf(accs[cg][4 * q + 0] + bb.x, 0.f);
            float e1 = fmaxf(accs[cg][4 * q + 1] + bb.y, 0.f);
            float e2 = fmaxf(accs[cg][4 * q + 2] + bb.z, 0.f);
            float e3 = fmaxf(accs[cg][4 * q + 3] + bb.w, 0.f);
            *(uint2*)&lds[hbase + (l31 & 15) * 256 + ((((cg << 2) + q) ^ swz) << 4) + hi * 8] =
                make_uint2(pk2(e0, e1), pk2(e2, e3));
          }
      }
      const int rbase = half * 16;
#pragma unroll
      for (int r = 0; r < 16; ++r) {
        int sid = __builtin_amdgcn_readlane(scur, rbase + r);
        if (sid != cur) {
          if (cur >= 0) {
            atomicAdd(&seg_sum[cur * 128 + 2 * lane], s0);
            atomicAdd(&seg_sum[cur * 128 + 2 * lane + 1], s1);
            atomicMax(&seg_max[cur * 128 + 2 * lane], __float_as_int(m0));
            atomicMax(&seg_max[cur * 128 + 2 * lane + 1], __float_as_int(m1));
            if (lane == 0) atomicAdd(&seg_cnt[cur], (u32)cnt);
          }
          s0 = s1 = m0 = m1 = 0.f; cnt = 0; cur = sid;
        }
        if (cur >= 0) {
          u32 pv = *(const u32*)&lds[hbase + r * 256 + ((((lane >> 2) ^ r) & 15) << 4) +
                                     (lane & 3) * 4];
          float v0 = bf2f(pv & 0xffffu);
          float v1 = bf2f(pv >> 16);
          s0 += v0; s1 += v1;
          m0 = fmaxf(m0, v0); m1 = fmaxf(m1, v1);
          ++cnt;
        }
      }
    }
    if (cur >= 0) {  // final flush
      atomicAdd(&seg_sum[cur * 128 + 2 * lane], s0);
      atomicAdd(&seg_sum[cur * 128 + 2 * lane + 1], s1);
      atomicMax(&seg_max[cur * 128 + 2 * lane], __float_as_int(m0));
      atomicMax(&seg_max[cur * 128 + 2 * lane + 1], __float_as_int(m1));
      if (lane == 0) atomicAdd(&seg_cnt[cur], (u32)cnt);
    }
  }
}

// out[s,o] = BN( [sum|max|mean] @ Wo^T + bo )
__global__ __launch_bounds__(128)
void proj_kernel(const float* __restrict__ seg_sum, const unsigned* __restrict__ seg_max,
                 const u32* __restrict__ seg_cnt,
                 const float* __restrict__ Wo, const float* __restrict__ bo,
                 const float* __restrict__ go, const float* __restrict__ beo,
                 const float* __restrict__ mo, const float* __restrict__ vo,
                 float* __restrict__ out) {
  __shared__ __attribute__((aligned(16))) float agg[384];
  __shared__ float part[64];
  const int s = blockIdx.x, t = threadIdx.x;
  float cinv = 1.f / fmaxf((float)seg_cnt[s], 1.f);
  for (int i = t; i < 384; i += 128) {
    float v;
    if (i < 128)      v = seg_sum[s * 128 + i];
    else if (i < 256) v = __uint_as_float(seg_max[s * 128 + i - 128]);
    else              v = seg_sum[s * 128 + i - 256] * cinv;
    agg[i] = v;
  }
  __syncthreads();
  const int o = t & 63, hf = t >> 6;
  const float4* wrow = (const float4*)(Wo + o * 384 + hf * 192);
  float acc = 0.f;
#pragma unroll 8
  for (int k4 = 0; k4 < 48; ++k4) {
    float4 w = wrow[k4];
    float4 a = *(const float4*)&agg[hf * 192 + k4 * 4];
    acc += w.x * a.x + w.y * a.y + w.z * a.z + w.w * a.w;
  }
  if (hf) part[o] = acc;
  __syncthreads();
  if (!hf) {
    acc += part[o];
    float sc = go[o] * rsqrtf(vo[o] + EPSF);
    out[s * 64 + o] = (acc + bo[o] - mo[o]) * sc + beo[o];
  }
}

extern "C" void kernel_launch(void* const* d_in, const int* in_sizes, int n_in,
                              void* d_out, int out_size, void* d_ws, size_t ws_size,
                              hipStream_t stream) {
  (void)n_in; (void)out_size; (void)ws_size;
  const float* x = (const float*)d_in[0];
  const int* batch = (const int*)d_in[1];
  LayerP P0{(const float*)d_in[2],  (const float*)d_in[3],  (const float*)d_in[4],
            (const float*)d_in[5],  (const float*)d_in[6],  (const float*)d_in[7]};
  LayerP P1{(const float*)d_in[8],  (const float*)d_in[9],  (const float*)d_in[10],
            (const float*)d_in[11], (const float*)d_in[12], (const float*)d_in[13]};
  LayerP P2{(const float*)d_in[14], (const float*)d_in[15], (const float*)d_in[16],
            (const float*)d_in[17], (const float*)d_in[18], (const float*)d_in[19]};
  const float* Wo  = (const float*)d_in[20];
  const float* bo  = (const float*)d_in[21];
  const float* go  = (const float*)d_in[22];
  const float* beo = (const float*)d_in[23];
  const float* mo  = (const float*)d_in[24];
  const float* vo  = (const float*)d_in[25];
  const int N = in_sizes[0] / 128;

  char* ws = (char*)d_ws;
  float* seg_sum = (float*)ws;                         // 1 MiB
  int*   seg_max = (int*)(ws + (1u << 20));            // 1 MiB (float bits, >=0)
  u32*   seg_cnt = (u32*)(ws + (2u << 20));            // 8 KiB
  unsigned short* wsW = (unsigned short*)(ws + (2u << 20) + 8192);  // 96 KiB
  float* biasf = (float*)(ws + (2u << 20) + 8192 + 98304);          // 1.5 KiB

  hipMemsetAsync(d_ws, 0, (size_t)(2u << 20) + 8192, stream);
  prep_kernel<<<3, 256, 0, stream>>>(P0, P1, P2, wsW, biasf);
  const int ntiles = (N + 31) / 32;
  enc_kernel<<<NBLK, NTHR, 0, stream>>>(x, batch, wsW, biasf, seg_sum, seg_max, seg_cnt,
                                        N, ntiles);
  proj_kernel<<<NSEG, 128, 0, stream>>>(seg_sum, (const unsigned*)seg_max, seg_cnt,
                                        Wo, bo, go, beo, mo, vo, (float*)d_out);
}